// Round 3
// baseline (714.091 us; speedup 1.0000x reference)
//
#include <hip/hip_runtime.h>
#include <hip/hip_bf16.h>

constexpr int B  = 8,  P = 50, N = 128, M = 128;
constexpr int EMB = 128, H = 8, D = 16;
constexpr int NE = 8;
constexpr int HD = H * D;        // 128
constexpr int E1 = EMB + 1;      // 129
constexpr int BP = B * P;        // 400
constexpr int T  = BP * N;       // 51200 tokens

typedef __hip_bfloat16 bf16;

// dual-dtype input load: flag==1 -> tensor is f32, flag==0 -> bf16
__device__ __forceinline__ float ldx(const void* p, long i, int f32f) {
    return f32f ? ((const float*)p)[i]
                : __bfloat162float(((const bf16*)p)[i]);
}

// ---------------------------------------------------------------------------
// K_det: decide input dtype. Reading f32 data as bf16 makes even-indexed
// elements garbage (uniform exponent, ~16% "sane"); bf16 data gives sane
// N(0,1) values (~100% sane).
// ---------------------------------------------------------------------------
__global__ void detect_kernel(const void* nodes, int* flag) {
    if (threadIdx.x == 0) {
        int sane = 0;
        const bf16* p = (const bf16*)nodes;
        for (int i = 0; i < 64; ++i) {
            float v = __bfloat162float(p[2 * i]);
            float a = fabsf(v);
            if (v == 0.0f || (a > 9.5e-7f && a < 1.0e6f)) ++sane;
        }
        *flag = (sane >= 56) ? 0 : 1;   // 0 = bf16 inputs, 1 = f32 inputs
    }
}

// ---------------------------------------------------------------------------
// K0: We'[e][f] = sum_o We[e][f][o] * Wfinal[o];  b'[e] = be[e] . Wfinal.
// Also zeroes importance. grid NE, block 128.
// ---------------------------------------------------------------------------
__global__ void prep_kernel(const void* We, const void* be, const void* Wf,
                            const int* __restrict__ flag,
                            float* __restrict__ Wep, float* __restrict__ bpv,
                            float* __restrict__ importance) {
    const int e = blockIdx.x;
    const int f = threadIdx.x;
    const int f32f = *flag;

    float a = 0.f;
    const long base = ((long)e * HD + f) * E1;
    for (int o = 0; o < E1; ++o)
        a += ldx(We, base + o, f32f) * ldx(Wf, o, f32f);
    Wep[e * HD + f] = a;

    if (f == 0) {
        float b = 0.f;
        for (int o = 0; o < E1; ++o)
            b += ldx(be, (long)e * E1 + o, f32f) * ldx(Wf, o, f32f);
        bpv[e] = b;
    }
    if (e == 0 && f < NE) importance[f] = 0.f;
}

// ---------------------------------------------------------------------------
// K1: fused QKV projection + masked attention for one (bp, head).
// grid (BP, H), block 128 (thread = query row n, also = route row m).
// LDS ~40 KB. All math f32.
// ---------------------------------------------------------------------------
__global__ void qkv_attn_kernel(const void* nodes, const void* routes,
                                const void* Wq, const void* Wk, const void* Wv,
                                const void* rmask, const void* ninf,
                                const int* __restrict__ flag,
                                float* __restrict__ xcat) {
    const int bp = blockIdx.x;
    const int h  = blockIdx.y;
    const int n  = threadIdx.x;
    const int f32f = *flag;

    __shared__ float WqS[EMB][D];   // 8 KB
    __shared__ float WkS[E1][D];    // 8.0625 KB
    __shared__ float WvS[E1][D];    // 8.0625 KB
    __shared__ float kh[M][D];      // 8 KB
    __shared__ float vh[M][D];      // 8 KB

    // stage per-head weight slices
    for (int idx = n; idx < EMB * D; idx += N) {
        int f = idx >> 4, d = idx & 15;
        WqS[f][d] = ldx(Wq, (long)f * HD + h * D + d, f32f);
    }
    for (int idx = n; idx < E1 * D; idx += N) {
        int f = idx >> 4, d = idx & 15;
        WkS[f][d] = ldx(Wk, (long)f * HD + h * D + d, f32f);
        WvS[f][d] = ldx(Wv, (long)f * HD + h * D + d, f32f);
    }
    __syncthreads();

    // k_h, v_h for route row m = n
    {
        float ka[D], va[D];
        #pragma unroll
        for (int d = 0; d < D; ++d) { ka[d] = 0.f; va[d] = 0.f; }
        const long rbase = ((long)bp * M + n) * E1;
        for (int f = 0; f < E1; ++f) {
            float r = ldx(routes, rbase + f, f32f);
            #pragma unroll
            for (int d = 0; d < D; ++d) {
                ka[d] += r * WkS[f][d];
                va[d] += r * WvS[f][d];
            }
        }
        #pragma unroll
        for (int d = 0; d < D; ++d) { kh[n][d] = ka[d]; vh[n][d] = va[d]; }
    }

    // q for query row n (registers)
    float qr[D];
    #pragma unroll
    for (int d = 0; d < D; ++d) qr[d] = 0.f;
    {
        const long nbase = ((long)bp * N + n) * EMB;
        for (int f = 0; f < EMB; ++f) {
            float x = ldx(nodes, nbase + f, f32f);
            #pragma unroll
            for (int d = 0; d < D; ++d) qr[d] += x * WqS[f][d];
        }
    }
    __syncthreads();

    // attention: scores bounded (~|s|<1 with zero masks), exp w/o max-sub safe
    float sum = 0.f;
    float acc[D];
    #pragma unroll
    for (int d = 0; d < D; ++d) acc[d] = 0.f;
    const long rmb = ((long)bp * N + n) * M;
    for (int m = 0; m < M; ++m) {
        float s = 0.f;
        #pragma unroll
        for (int d = 0; d < D; ++d) s += qr[d] * kh[m][d];
        s = s * 0.25f + ldx(rmask, rmb + m, f32f);
        float e = __expf(s);
        sum += e;
        #pragma unroll
        for (int d = 0; d < D; ++d) acc[d] += e * vh[m][d];
    }

    float keep = (ldx(ninf, (long)bp * N + n, f32f) == 0.f) ? 1.f : 0.f;
    float inv  = keep / sum;
    const long ob = ((long)bp * N + n) * HD + h * D;
    #pragma unroll
    for (int d = 0; d < D; ++d) xcat[ob + d] = acc[d] * inv;
}

// ---------------------------------------------------------------------------
// K2: fused MoE gating + collapsed expert scoring + final softmax.
// grid BP, block 128 (thread = token n). score = sum_e g_e*(x.We'[e] + b'[e]).
// ---------------------------------------------------------------------------
__global__ void moe_final_kernel(const float* __restrict__ xcat,
                                 const void* Wg, const void* ninf,
                                 const float* __restrict__ Wep,
                                 const float* __restrict__ bpv,
                                 const int* __restrict__ flag,
                                 float* __restrict__ importance,
                                 float* __restrict__ out) {
    __shared__ float WgS[EMB][NE];   // 4 KB
    __shared__ float WeS[NE][HD];    // 4 KB
    __shared__ float red[N];
    __shared__ float impS[NE];

    const int bp = blockIdx.x;
    const int n  = threadIdx.x;
    const int f32f = *flag;

    for (int idx = n; idx < EMB * NE; idx += N)
        WgS[idx >> 3][idx & 7] = ldx(Wg, idx, f32f);       // Wg is [f][e] row-major
    for (int idx = n; idx < NE * HD; idx += N)
        WeS[idx >> 7][idx & 127] = Wep[idx];
    if (n < NE) impS[n] = 0.f;
    __syncthreads();

    const long t = (long)bp * N + n;
    const float* row = xcat + t * HD;

    // gate logits (f32 end-to-end; top-k selection must match np)
    float gl[NE];
    #pragma unroll
    for (int e = 0; e < NE; ++e) gl[e] = 0.f;
    for (int f = 0; f < EMB; ++f) {
        float x = row[f];
        #pragma unroll
        for (int e = 0; e < NE; ++e) gl[e] += x * WgS[f][e];
    }

    // top-2 (first-occurrence tie-break, like jax.lax.top_k)
    int e0 = 0; float v0 = gl[0];
    #pragma unroll
    for (int e = 1; e < NE; ++e) if (gl[e] > v0) { v0 = gl[e]; e0 = e; }
    int e1 = -1; float v1 = -3.4e38f;
    #pragma unroll
    for (int e = 0; e < NE; ++e) if (e != e0 && gl[e] > v1) { v1 = gl[e]; e1 = e; }
    float ex = __expf(v1 - v0);
    float g0 = 1.f / (1.f + ex);
    float g1 = ex / (1.f + ex);

    atomicAdd(&impS[e0], g0);
    atomicAdd(&impS[e1], g1);

    // collapsed expert scoring: s = sum_e g_e * (x . We'[e] + b'[e])
    float s = g0 * bpv[e0] + g1 * bpv[e1];
    for (int f = 0; f < EMB; ++f)
        s += row[f] * (g0 * WeS[e0][f] + g1 * WeS[e1][f]);
    s = 10.f * tanhf(s) + ldx(ninf, t, f32f);

    // softmax over the 128 tokens of this (b,p)
    red[n] = s;
    __syncthreads();
    for (int off = 64; off > 0; off >>= 1) {
        if (n < off) red[n] = fmaxf(red[n], red[n + off]);
        __syncthreads();
    }
    float mx = red[0];
    __syncthreads();
    float e = __expf(s - mx);
    red[n] = e;
    __syncthreads();
    for (int off = 64; off > 0; off >>= 1) {
        if (n < off) red[n] += red[n + off];
        __syncthreads();
    }
    float sum = red[0];

    out[t] = e / sum;              // f32 output

    if (n < NE) atomicAdd(&importance[n], impS[n]);
}

// ---------------------------------------------------------------------------
// K3: moe_loss from importance (f32 output at out[T]).
// ---------------------------------------------------------------------------
__global__ void loss_kernel(const float* __restrict__ importance,
                            float* __restrict__ out) {
    if (threadIdx.x == 0) {
        float mean = 0.f;
        #pragma unroll
        for (int e = 0; e < NE; ++e) mean += importance[e];
        mean *= (1.f / NE);
        float var = 0.f;
        #pragma unroll
        for (int e = 0; e < NE; ++e) {
            float d = importance[e] - mean;
            var += d * d;
        }
        var *= (1.f / NE);
        out[T] = var / (mean * mean + 1e-10f);
    }
}

// ---------------------------------------------------------------------------
extern "C" void kernel_launch(void* const* d_in, const int* in_sizes, int n_in,
                              void* d_out, int out_size, void* d_ws, size_t ws_size,
                              hipStream_t stream) {
    const void* nodes  = d_in[0];
    const void* routes = d_in[1];
    const void* ninf   = d_in[2];
    const void* rmask  = d_in[3];
    const void* Wq     = d_in[4];
    const void* Wk     = d_in[5];
    const void* Wv     = d_in[6];
    const void* Wg     = d_in[7];
    const void* We     = d_in[8];
    const void* be     = d_in[9];
    const void* Wfin   = d_in[10];

    // ws layout (f32 elements): [0] flag | [16..1040) We' | [1040..1048) b' |
    // [1048..1056) importance | [2048..) xcat (T*HD = 6.55M floats, ~26 MB)
    float* ws = (float*)d_ws;
    int*   flag       = (int*)ws;
    float* Wep        = ws + 16;
    float* bpv        = ws + 1040;
    float* importance = ws + 1048;
    float* xcat       = ws + 2048;

    float* out = (float*)d_out;

    detect_kernel<<<1, 64, 0, stream>>>(nodes, flag);
    prep_kernel<<<NE, 128, 0, stream>>>(We, be, Wfin, flag, Wep, bpv, importance);
    qkv_attn_kernel<<<dim3(BP, H), 128, 0, stream>>>(nodes, routes, Wq, Wk, Wv,
                                                     rmask, ninf, flag, xcat);
    moe_final_kernel<<<BP, 128, 0, stream>>>(xcat, Wg, ninf, Wep, bpv, flag,
                                             importance, out);
    loss_kernel<<<1, 64, 0, stream>>>(importance, out);
}

// Round 4
// 379.638 us; speedup vs baseline: 1.8810x; 1.8810x over previous
//
#include <hip/hip_runtime.h>

constexpr int B  = 8,  P = 50, N = 128, M = 128;
constexpr int EMB = 128, H = 8, D = 16;
constexpr int NE = 8;
constexpr int HD = H * D;        // 128
constexpr int E1 = EMB + 1;      // 129
constexpr int BP = B * P;        // 400
constexpr int T  = BP * N;       // 51200 tokens

// ---------------------------------------------------------------------------
// K0: We'[e][f] = sum_o We[e][f][o]*Wfinal[o]; b'[e] = be[e].Wfinal.
// Also zeroes importance. grid NE, block 128.
// ---------------------------------------------------------------------------
__global__ void prep_kernel(const float* __restrict__ We,
                            const float* __restrict__ be,
                            const float* __restrict__ Wf,
                            float* __restrict__ Wep, float* __restrict__ bpv,
                            float* __restrict__ importance) {
    const int e = blockIdx.x;
    const int f = threadIdx.x;

    float a = 0.f;
    const long base = ((long)e * HD + f) * E1;
    for (int o = 0; o < E1; ++o) a += We[base + o] * Wf[o];
    Wep[e * HD + f] = a;

    if (f == 0) {
        float b = 0.f;
        for (int o = 0; o < E1; ++o) b += be[(long)e * E1 + o] * Wf[o];
        bpv[e] = b;
    }
    if (e == 0 && f < NE) importance[f] = 0.f;
}

// ---------------------------------------------------------------------------
// K1: k = routes@Wk, v = routes@Wv  (f32 register-tiled GEMM, K=129).
// grid (800, 2), block 128. Tile: 64 rows x 128 cols, 8x8 acc per thread.
// ---------------------------------------------------------------------------
__global__ __launch_bounds__(128) void proj_kernel(
    const float* __restrict__ X,      // routes [T][129]
    const float* __restrict__ Wk,     // [129][128]
    const float* __restrict__ Wv,
    float* __restrict__ ko, float* __restrict__ vo) {
    const int mat  = blockIdx.y;
    const float* __restrict__ W = mat ? Wv : Wk;
    float* __restrict__ out     = mat ? vo : ko;
    const int row0 = blockIdx.x * 64;
    const int tid  = threadIdx.x;
    const int tr   = tid >> 4;        // 0..7  -> rows tr*4..+3 and +32
    const int tc   = tid & 15;        // 0..15 -> cols tc*4..+3 and +64

    __shared__ float XT[8][68];       // [k][row], padded
    __shared__ float WS[8][132];      // [k][col], padded

    float acc[8][8];
    #pragma unroll
    for (int i = 0; i < 8; ++i)
        #pragma unroll
        for (int j = 0; j < 8; ++j) acc[i][j] = 0.f;

    for (int kk = 0; kk < E1; kk += 8) {
        const int kw = (E1 - kk) < 8 ? (E1 - kk) : 8;
        // stage X tile (64 rows x kw), k-major transposed in LDS
        #pragma unroll
        for (int i = 0; i < 4; ++i) {
            int e = tid + i * 128;
            int kx = e & 7, r = e >> 3;
            XT[kx][r] = (kx < kw) ? X[(long)(row0 + r) * E1 + kk + kx] : 0.f;
        }
        // stage W tile (kw x 128), coalesced float4
        #pragma unroll
        for (int i = 0; i < 2; ++i) {
            int e  = tid + i * 128;            // float4 index
            int kx = e >> 5, c4 = (e & 31) * 4;
            float4 w4 = make_float4(0.f, 0.f, 0.f, 0.f);
            if (kx < kw) w4 = *(const float4*)&W[(long)(kk + kx) * HD + c4];
            *(float4*)&WS[kx][c4] = w4;
        }
        __syncthreads();

        #pragma unroll
        for (int k = 0; k < 8; ++k) {
            float4 xa = *(const float4*)&XT[k][tr * 4];
            float4 xb = *(const float4*)&XT[k][32 + tr * 4];
            float4 wa = *(const float4*)&WS[k][tc * 4];
            float4 wb = *(const float4*)&WS[k][64 + tc * 4];
            float xr[8] = {xa.x, xa.y, xa.z, xa.w, xb.x, xb.y, xb.z, xb.w};
            float wc[8] = {wa.x, wa.y, wa.z, wa.w, wb.x, wb.y, wb.z, wb.w};
            #pragma unroll
            for (int i = 0; i < 8; ++i)
                #pragma unroll
                for (int j = 0; j < 8; ++j) acc[i][j] += xr[i] * wc[j];
        }
        __syncthreads();
    }

    #pragma unroll
    for (int ig = 0; ig < 2; ++ig)
        #pragma unroll
        for (int i = 0; i < 4; ++i) {
            int r = row0 + ig * 32 + tr * 4 + i;
            float4 o0 = make_float4(acc[ig*4+i][0], acc[ig*4+i][1],
                                    acc[ig*4+i][2], acc[ig*4+i][3]);
            float4 o1 = make_float4(acc[ig*4+i][4], acc[ig*4+i][5],
                                    acc[ig*4+i][6], acc[ig*4+i][7]);
            *(float4*)&out[(long)r * HD + tc * 4]      = o0;
            *(float4*)&out[(long)r * HD + 64 + tc * 4] = o1;
        }
}

// ---------------------------------------------------------------------------
// K2: fused q-projection + masked attention per (bp, head).
// grid (400, 8), block 64. Each thread owns query rows n0=tid, n1=tid+64
// (2 rows amortize the wave-uniform kh/vh LDS broadcasts -> VALU-bound).
// ---------------------------------------------------------------------------
__global__ __launch_bounds__(64) void attn_kernel(
    const float* __restrict__ nodes,  // [T][128]
    const float* __restrict__ Wq,     // [128][128]
    const float* __restrict__ kbuf,   // [T][128]
    const float* __restrict__ vbuf,   // [T][128]
    const float* __restrict__ rmask,  // [BP*N][M]
    const float* __restrict__ ninf,   // [BP*N]
    float* __restrict__ xcat) {       // [T][128]
    const int bp  = blockIdx.x;
    const int h   = blockIdx.y;
    const int tid = threadIdx.x;

    __shared__ float WqS[EMB][D];   // 8 KB
    __shared__ float kh[M][D];      // 8 KB
    __shared__ float vh[M][D];      // 8 KB

    #pragma unroll
    for (int i = 0; i < 8; ++i) {
        int e = tid + i * 64;        // float4 index (512 total)
        int r = e >> 2, c4 = (e & 3) * 4;
        *(float4*)&WqS[r][c4] = *(const float4*)&Wq[(long)r * HD + h * D + c4];
        *(float4*)&kh[r][c4]  = *(const float4*)&kbuf[((long)bp * M + r) * HD + h * D + c4];
        *(float4*)&vh[r][c4]  = *(const float4*)&vbuf[((long)bp * M + r) * HD + h * D + c4];
    }
    __syncthreads();

    const int n0 = tid, n1 = tid + 64;
    const long t0 = (long)bp * N + n0, t1 = (long)bp * N + n1;

    // q projection for two rows (scale 1/sqrt(D)=0.25 folded in afterwards)
    float qr0[16], qr1[16];
    #pragma unroll
    for (int d = 0; d < 16; ++d) { qr0[d] = 0.f; qr1[d] = 0.f; }
    const float4* x0 = (const float4*)&nodes[t0 * EMB];
    const float4* x1 = (const float4*)&nodes[t1 * EMB];
    for (int fb = 0; fb < 32; ++fb) {
        float4 a = x0[fb], b = x1[fb];
        float av[4] = {a.x, a.y, a.z, a.w};
        float bv[4] = {b.x, b.y, b.z, b.w};
        #pragma unroll
        for (int j = 0; j < 4; ++j) {
            const float4* w4 = (const float4*)&WqS[fb * 4 + j][0];
            #pragma unroll
            for (int q4 = 0; q4 < 4; ++q4) {
                float4 w = w4[q4];
                qr0[q4*4+0] += av[j] * w.x; qr0[q4*4+1] += av[j] * w.y;
                qr0[q4*4+2] += av[j] * w.z; qr0[q4*4+3] += av[j] * w.w;
                qr1[q4*4+0] += bv[j] * w.x; qr1[q4*4+1] += bv[j] * w.y;
                qr1[q4*4+2] += bv[j] * w.z; qr1[q4*4+3] += bv[j] * w.w;
            }
        }
    }
    #pragma unroll
    for (int d = 0; d < 16; ++d) { qr0[d] *= 0.25f; qr1[d] *= 0.25f; }

    // attention (exp without max-sub: scores bounded, -inf masks -> exp=0)
    float sum0 = 0.f, sum1 = 0.f;
    float o0[16], o1[16];
    #pragma unroll
    for (int d = 0; d < 16; ++d) { o0[d] = 0.f; o1[d] = 0.f; }
    const float4* rm0 = (const float4*)&rmask[t0 * M];
    const float4* rm1 = (const float4*)&rmask[t1 * M];
    for (int mb = 0; mb < 32; ++mb) {
        float4 r0 = rm0[mb], r1 = rm1[mb];
        float r0v[4] = {r0.x, r0.y, r0.z, r0.w};
        float r1v[4] = {r1.x, r1.y, r1.z, r1.w};
        #pragma unroll
        for (int j = 0; j < 4; ++j) {
            const int m = mb * 4 + j;
            const float4* k4 = (const float4*)&kh[m][0];
            const float4* v4 = (const float4*)&vh[m][0];
            float s0 = 0.f, s1 = 0.f;
            #pragma unroll
            for (int q4 = 0; q4 < 4; ++q4) {
                float4 kq = k4[q4];
                s0 += qr0[q4*4+0]*kq.x + qr0[q4*4+1]*kq.y
                    + qr0[q4*4+2]*kq.z + qr0[q4*4+3]*kq.w;
                s1 += qr1[q4*4+0]*kq.x + qr1[q4*4+1]*kq.y
                    + qr1[q4*4+2]*kq.z + qr1[q4*4+3]*kq.w;
            }
            float e0 = __expf(s0 + r0v[j]);
            float e1 = __expf(s1 + r1v[j]);
            sum0 += e0; sum1 += e1;
            #pragma unroll
            for (int q4 = 0; q4 < 4; ++q4) {
                float4 vq = v4[q4];
                o0[q4*4+0] += e0*vq.x; o0[q4*4+1] += e0*vq.y;
                o0[q4*4+2] += e0*vq.z; o0[q4*4+3] += e0*vq.w;
                o1[q4*4+0] += e1*vq.x; o1[q4*4+1] += e1*vq.y;
                o1[q4*4+2] += e1*vq.z; o1[q4*4+3] += e1*vq.w;
            }
        }
    }

    const float inv0 = ((ninf[t0] == 0.f) ? 1.f : 0.f) / sum0;
    const float inv1 = ((ninf[t1] == 0.f) ? 1.f : 0.f) / sum1;
    #pragma unroll
    for (int q4 = 0; q4 < 4; ++q4) {
        float4 w0 = make_float4(o0[q4*4+0]*inv0, o0[q4*4+1]*inv0,
                                o0[q4*4+2]*inv0, o0[q4*4+3]*inv0);
        float4 w1 = make_float4(o1[q4*4+0]*inv1, o1[q4*4+1]*inv1,
                                o1[q4*4+2]*inv1, o1[q4*4+3]*inv1);
        *(float4*)&xcat[t0 * HD + h * D + q4 * 4] = w0;
        *(float4*)&xcat[t1 * HD + h * D + q4 * 4] = w1;
    }
}

// ---------------------------------------------------------------------------
// K3: MoE gating (top-2) + collapsed expert scoring + final softmax.
// grid BP, block 128 (thread = token n).
// ---------------------------------------------------------------------------
__global__ __launch_bounds__(128) void moe_final_kernel(
    const float* __restrict__ xcat, const float* __restrict__ Wg,
    const float* __restrict__ ninf, const float* __restrict__ Wep,
    const float* __restrict__ bpv, float* __restrict__ importance,
    float* __restrict__ out) {
    __shared__ float WgS[EMB][NE];   // 4 KB
    __shared__ float WeS[NE][132];   // padded: divergent expert reads conflict-free
    __shared__ float red[N];
    __shared__ float impS[NE];

    const int bp = blockIdx.x;
    const int n  = threadIdx.x;

    #pragma unroll
    for (int i = 0; i < 2; ++i) {    // WgS: 1024 floats = 256 f4
        int e = n + i * 128;
        int r = e >> 1, c4 = (e & 1) * 4;
        *(float4*)&WgS[r][c4] = *(const float4*)&Wg[(long)r * NE + c4];
    }
    #pragma unroll
    for (int i = 0; i < 2; ++i) {    // WeS: 1024 floats = 256 f4
        int idx = n + i * 128;
        int r = idx >> 5, c = (idx & 31) * 4;
        *(float4*)&WeS[r][c] = *(const float4*)&Wep[(long)r * HD + c];
    }
    if (n < NE) impS[n] = 0.f;
    __syncthreads();

    const long t = (long)bp * N + n;
    const float4* row4 = (const float4*)&xcat[t * HD];

    // gate logits (f32 end-to-end; top-k selection must match np)
    float gl[NE];
    #pragma unroll
    for (int e = 0; e < NE; ++e) gl[e] = 0.f;
    for (int fb = 0; fb < 32; ++fb) {
        float4 xv = row4[fb];
        float x4[4] = {xv.x, xv.y, xv.z, xv.w};
        #pragma unroll
        for (int j = 0; j < 4; ++j)
            #pragma unroll
            for (int e = 0; e < NE; ++e) gl[e] += x4[j] * WgS[fb * 4 + j][e];
    }

    // top-2 (first-occurrence tie-break, like jax.lax.top_k)
    int e0 = 0; float v0 = gl[0];
    #pragma unroll
    for (int e = 1; e < NE; ++e) if (gl[e] > v0) { v0 = gl[e]; e0 = e; }
    int e1 = -1; float v1 = -3.4e38f;
    #pragma unroll
    for (int e = 0; e < NE; ++e) if (e != e0 && gl[e] > v1) { v1 = gl[e]; e1 = e; }
    float ex = __expf(v1 - v0);
    float g0 = 1.f / (1.f + ex);
    float g1 = ex / (1.f + ex);

    atomicAdd(&impS[e0], g0);
    atomicAdd(&impS[e1], g1);

    // collapsed expert scoring: s = sum_e g_e * (x . We'[e] + b'[e])
    float s = g0 * bpv[e0] + g1 * bpv[e1];
    for (int fb = 0; fb < 32; ++fb) {
        float4 xv = row4[fb];
        float x4[4] = {xv.x, xv.y, xv.z, xv.w};
        #pragma unroll
        for (int j = 0; j < 4; ++j) {
            int f = fb * 4 + j;
            s += x4[j] * (g0 * WeS[e0][f] + g1 * WeS[e1][f]);
        }
    }
    s = 10.f * tanhf(s) + ninf[t];

    // softmax over the 128 tokens of this (b,p)
    red[n] = s;
    __syncthreads();
    for (int off = 64; off > 0; off >>= 1) {
        if (n < off) red[n] = fmaxf(red[n], red[n + off]);
        __syncthreads();
    }
    float mx = red[0];
    __syncthreads();
    float e = __expf(s - mx);
    red[n] = e;
    __syncthreads();
    for (int off = 64; off > 0; off >>= 1) {
        if (n < off) red[n] += red[n + off];
        __syncthreads();
    }
    float sum = red[0];

    out[t] = e / sum;

    if (n < NE) atomicAdd(&importance[n], impS[n]);
}

// ---------------------------------------------------------------------------
// K4: moe_loss from importance (f32 at out[T]).
// ---------------------------------------------------------------------------
__global__ void loss_kernel(const float* __restrict__ importance,
                            float* __restrict__ out) {
    if (threadIdx.x == 0) {
        float mean = 0.f;
        #pragma unroll
        for (int e = 0; e < NE; ++e) mean += importance[e];
        mean *= (1.f / NE);
        float var = 0.f;
        #pragma unroll
        for (int e = 0; e < NE; ++e) {
            float d = importance[e] - mean;
            var += d * d;
        }
        var *= (1.f / NE);
        out[T] = var / (mean * mean + 1e-10f);
    }
}

// ---------------------------------------------------------------------------
extern "C" void kernel_launch(void* const* d_in, const int* in_sizes, int n_in,
                              void* d_out, int out_size, void* d_ws, size_t ws_size,
                              hipStream_t stream) {
    const float* nodes  = (const float*)d_in[0];
    const float* routes = (const float*)d_in[1];
    const float* ninf   = (const float*)d_in[2];
    const float* rmask  = (const float*)d_in[3];
    const float* Wq     = (const float*)d_in[4];
    const float* Wk     = (const float*)d_in[5];
    const float* Wv     = (const float*)d_in[6];
    const float* Wg     = (const float*)d_in[7];
    const float* We     = (const float*)d_in[8];
    const float* be     = (const float*)d_in[9];
    const float* Wfin   = (const float*)d_in[10];

    // ws (f32 elems): [16..1040) We' | [1040..1048) b' | [1048..1056) importance
    // | [4096..) k | +T*HD v | +2*T*HD xcat   (total ~78.7 MB)
    float* ws = (float*)d_ws;
    float* Wep        = ws + 16;
    float* bpv        = ws + 1040;
    float* importance = ws + 1048;
    float* kbuf       = ws + 4096;
    float* vbuf       = kbuf + (long)T * HD;
    float* xcat       = vbuf + (long)T * HD;

    float* out = (float*)d_out;

    prep_kernel<<<NE, 128, 0, stream>>>(We, be, Wfin, Wep, bpv, importance);
    proj_kernel<<<dim3(800, 2), 128, 0, stream>>>(routes, Wk, Wv, kbuf, vbuf);
    attn_kernel<<<dim3(BP, H), 64, 0, stream>>>(nodes, Wq, kbuf, vbuf,
                                                rmask, ninf, xcat);
    moe_final_kernel<<<BP, 128, 0, stream>>>(xcat, Wg, ninf, Wep, bpv,
                                             importance, out);
    loss_kernel<<<1, 64, 0, stream>>>(importance, out);
}

// Round 5
// 307.800 us; speedup vs baseline: 2.3200x; 1.2334x over previous
//
#include <hip/hip_runtime.h>

constexpr int B  = 8,  P = 50, N = 128, M = 128;
constexpr int EMB = 128, H = 8, D = 16;
constexpr int NE = 8;
constexpr int HD = H * D;        // 128
constexpr int E1 = EMB + 1;      // 129
constexpr int BP = B * P;        // 400
constexpr int T  = BP * N;       // 51200 tokens

// ---------------------------------------------------------------------------
// K0: We'[e][f] = sum_o We[e][f][o]*Wfinal[o]; b'[e] = be[e].Wfinal.
// Also zeroes importance. grid NE, block 128.
// ---------------------------------------------------------------------------
__global__ void prep_kernel(const float* __restrict__ We,
                            const float* __restrict__ be,
                            const float* __restrict__ Wf,
                            float* __restrict__ Wep, float* __restrict__ bpv,
                            float* __restrict__ importance) {
    const int e = blockIdx.x;
    const int f = threadIdx.x;

    float a = 0.f;
    const long base = ((long)e * HD + f) * E1;
    for (int o = 0; o < E1; ++o) a += We[base + o] * Wf[o];
    Wep[e * HD + f] = a;

    if (f == 0) {
        float b = 0.f;
        for (int o = 0; o < E1; ++o) b += be[(long)e * E1 + o] * Wf[o];
        bpv[e] = b;
    }
    if (e == 0 && f < NE) importance[f] = 0.f;
}

// ---------------------------------------------------------------------------
// K1: q = nodes@Wq (K=128), k = routes@Wk, v = routes@Wv (K=129).
// grid (800, 3), block 128. Tile: 64 rows x 128 cols, 8x8 acc per thread.
// ---------------------------------------------------------------------------
__global__ __launch_bounds__(128) void proj_kernel(
    const float* __restrict__ nodes,  // [T][128]
    const float* __restrict__ routes, // [T][129]
    const float* __restrict__ Wq, const float* __restrict__ Wk,
    const float* __restrict__ Wv,
    float* __restrict__ qo, float* __restrict__ ko, float* __restrict__ vo) {
    const int mat = blockIdx.y;
    const float* __restrict__ X = (mat == 0) ? nodes : routes;
    const float* __restrict__ W = (mat == 0) ? Wq : (mat == 1 ? Wk : Wv);
    float* __restrict__ out     = (mat == 0) ? qo : (mat == 1 ? ko : vo);
    const int Kd = (mat == 0) ? EMB : E1;

    const int row0 = blockIdx.x * 64;
    const int tid  = threadIdx.x;
    const int tr   = tid >> 4;        // 0..7
    const int tc   = tid & 15;        // 0..15

    __shared__ float XT[8][68];       // [k][row], padded
    __shared__ float WS[8][132];      // [k][col], padded

    float acc[8][8];
    #pragma unroll
    for (int i = 0; i < 8; ++i)
        #pragma unroll
        for (int j = 0; j < 8; ++j) acc[i][j] = 0.f;

    for (int kk = 0; kk < Kd; kk += 8) {
        const int kw = (Kd - kk) < 8 ? (Kd - kk) : 8;
        #pragma unroll
        for (int i = 0; i < 4; ++i) {
            int e = tid + i * 128;
            int kx = e & 7, r = e >> 3;
            XT[kx][r] = (kx < kw) ? X[(long)(row0 + r) * Kd + kk + kx] : 0.f;
        }
        #pragma unroll
        for (int i = 0; i < 2; ++i) {
            int e  = tid + i * 128;            // float4 index
            int kx = e >> 5, c4 = (e & 31) * 4;
            float4 w4 = make_float4(0.f, 0.f, 0.f, 0.f);
            if (kx < kw) w4 = *(const float4*)&W[(long)(kk + kx) * HD + c4];
            *(float4*)&WS[kx][c4] = w4;
        }
        __syncthreads();

        #pragma unroll
        for (int k = 0; k < 8; ++k) {
            float4 xa = *(const float4*)&XT[k][tr * 4];
            float4 xb = *(const float4*)&XT[k][32 + tr * 4];
            float4 wa = *(const float4*)&WS[k][tc * 4];
            float4 wb = *(const float4*)&WS[k][64 + tc * 4];
            float xr[8] = {xa.x, xa.y, xa.z, xa.w, xb.x, xb.y, xb.z, xb.w};
            float wc[8] = {wa.x, wa.y, wa.z, wa.w, wb.x, wb.y, wb.z, wb.w};
            #pragma unroll
            for (int i = 0; i < 8; ++i)
                #pragma unroll
                for (int j = 0; j < 8; ++j) acc[i][j] += xr[i] * wc[j];
        }
        __syncthreads();
    }

    #pragma unroll
    for (int ig = 0; ig < 2; ++ig)
        #pragma unroll
        for (int i = 0; i < 4; ++i) {
            int r = row0 + ig * 32 + tr * 4 + i;
            float4 o0 = make_float4(acc[ig*4+i][0], acc[ig*4+i][1],
                                    acc[ig*4+i][2], acc[ig*4+i][3]);
            float4 o1 = make_float4(acc[ig*4+i][4], acc[ig*4+i][5],
                                    acc[ig*4+i][6], acc[ig*4+i][7]);
            *(float4*)&out[(long)r * HD + tc * 4]      = o0;
            *(float4*)&out[(long)r * HD + 64 + tc * 4] = o1;
        }
}

// ---------------------------------------------------------------------------
// K2: masked attention per (bp, head). grid (400, 8), block 64 (1 wave).
// Zero LDS: k/v rows are wave-uniform -> scalar/same-line loads from global.
// Each thread owns query rows n0=tid, n1=tid+64.
// ---------------------------------------------------------------------------
__global__ __launch_bounds__(64) void attn_kernel(
    const float* __restrict__ qbuf,   // [T][128]
    const float* __restrict__ kbuf,   // [T][128]
    const float* __restrict__ vbuf,   // [T][128]
    const float* __restrict__ rmask,  // [BP*N][M]
    const float* __restrict__ ninf,   // [BP*N]
    float* __restrict__ xcat) {       // [T][128]
    const int bp  = blockIdx.x;
    const int h   = blockIdx.y;
    const int tid = threadIdx.x;

    const long t0 = (long)bp * N + tid, t1 = t0 + 64;

    // q rows, 1/sqrt(D)=0.25 folded in
    float qr0[16], qr1[16];
    {
        const float4* q0 = (const float4*)&qbuf[t0 * HD + h * D];
        const float4* q1 = (const float4*)&qbuf[t1 * HD + h * D];
        #pragma unroll
        for (int i = 0; i < 4; ++i) {
            float4 a = q0[i], b = q1[i];
            qr0[i*4+0] = a.x*0.25f; qr0[i*4+1] = a.y*0.25f;
            qr0[i*4+2] = a.z*0.25f; qr0[i*4+3] = a.w*0.25f;
            qr1[i*4+0] = b.x*0.25f; qr1[i*4+1] = b.y*0.25f;
            qr1[i*4+2] = b.z*0.25f; qr1[i*4+3] = b.w*0.25f;
        }
    }

    const float* __restrict__ kbase = kbuf + ((long)bp * M) * HD + h * D;
    const float* __restrict__ vbase = vbuf + ((long)bp * M) * HD + h * D;
    const float4* rm0 = (const float4*)&rmask[t0 * M];
    const float4* rm1 = (const float4*)&rmask[t1 * M];

    float sum0 = 0.f, sum1 = 0.f;
    float o0[16], o1[16];
    #pragma unroll
    for (int d = 0; d < 16; ++d) { o0[d] = 0.f; o1[d] = 0.f; }

    for (int mb = 0; mb < 32; ++mb) {
        float4 r0 = rm0[mb], r1 = rm1[mb];
        float r0v[4] = {r0.x, r0.y, r0.z, r0.w};
        float r1v[4] = {r1.x, r1.y, r1.z, r1.w};
        #pragma unroll
        for (int j = 0; j < 4; ++j) {
            const int m = mb * 4 + j;
            const float4* k4 = (const float4*)&kbase[(long)m * HD];
            const float4* v4 = (const float4*)&vbase[(long)m * HD];
            float s0 = 0.f, s1 = 0.f;
            #pragma unroll
            for (int q4 = 0; q4 < 4; ++q4) {
                float4 kq = k4[q4];
                s0 += qr0[q4*4+0]*kq.x + qr0[q4*4+1]*kq.y
                    + qr0[q4*4+2]*kq.z + qr0[q4*4+3]*kq.w;
                s1 += qr1[q4*4+0]*kq.x + qr1[q4*4+1]*kq.y
                    + qr1[q4*4+2]*kq.z + qr1[q4*4+3]*kq.w;
            }
            float e0 = __expf(s0 + r0v[j]);
            float e1 = __expf(s1 + r1v[j]);
            sum0 += e0; sum1 += e1;
            #pragma unroll
            for (int q4 = 0; q4 < 4; ++q4) {
                float4 vq = v4[q4];
                o0[q4*4+0] += e0*vq.x; o0[q4*4+1] += e0*vq.y;
                o0[q4*4+2] += e0*vq.z; o0[q4*4+3] += e0*vq.w;
                o1[q4*4+0] += e1*vq.x; o1[q4*4+1] += e1*vq.y;
                o1[q4*4+2] += e1*vq.z; o1[q4*4+3] += e1*vq.w;
            }
        }
    }

    const float inv0 = ((ninf[t0] == 0.f) ? 1.f : 0.f) / sum0;
    const float inv1 = ((ninf[t1] == 0.f) ? 1.f : 0.f) / sum1;
    #pragma unroll
    for (int q4 = 0; q4 < 4; ++q4) {
        float4 w0 = make_float4(o0[q4*4+0]*inv0, o0[q4*4+1]*inv0,
                                o0[q4*4+2]*inv0, o0[q4*4+3]*inv0);
        float4 w1 = make_float4(o1[q4*4+0]*inv1, o1[q4*4+1]*inv1,
                                o1[q4*4+2]*inv1, o1[q4*4+3]*inv1);
        *(float4*)&xcat[t0 * HD + h * D + q4 * 4] = w0;
        *(float4*)&xcat[t1 * HD + h * D + q4 * 4] = w1;
    }
}

// ---------------------------------------------------------------------------
// K3: MoE gating (top-2) + collapsed expert scoring + final softmax.
// grid BP, block 128 (thread = token n).
// ---------------------------------------------------------------------------
__global__ __launch_bounds__(128) void moe_final_kernel(
    const float* __restrict__ xcat, const float* __restrict__ Wg,
    const float* __restrict__ ninf, const float* __restrict__ Wep,
    const float* __restrict__ bpv, float* __restrict__ importance,
    float* __restrict__ out) {
    __shared__ float WgS[EMB][NE];   // 4 KB
    __shared__ float WeS[NE][132];   // padded
    __shared__ float red[N];
    __shared__ float impS[NE];

    const int bp = blockIdx.x;
    const int n  = threadIdx.x;

    #pragma unroll
    for (int i = 0; i < 2; ++i) {
        int e = n + i * 128;
        int r = e >> 1, c4 = (e & 1) * 4;
        *(float4*)&WgS[r][c4] = *(const float4*)&Wg[(long)r * NE + c4];
    }
    #pragma unroll
    for (int i = 0; i < 2; ++i) {
        int idx = n + i * 128;
        int r = idx >> 5, c = (idx & 31) * 4;
        *(float4*)&WeS[r][c] = *(const float4*)&Wep[(long)r * HD + c];
    }
    if (n < NE) impS[n] = 0.f;
    __syncthreads();

    const long t = (long)bp * N + n;
    const float4* row4 = (const float4*)&xcat[t * HD];

    float gl[NE];
    #pragma unroll
    for (int e = 0; e < NE; ++e) gl[e] = 0.f;
    for (int fb = 0; fb < 32; ++fb) {
        float4 xv = row4[fb];
        float x4[4] = {xv.x, xv.y, xv.z, xv.w};
        #pragma unroll
        for (int j = 0; j < 4; ++j)
            #pragma unroll
            for (int e = 0; e < NE; ++e) gl[e] += x4[j] * WgS[fb * 4 + j][e];
    }

    int e0 = 0; float v0 = gl[0];
    #pragma unroll
    for (int e = 1; e < NE; ++e) if (gl[e] > v0) { v0 = gl[e]; e0 = e; }
    int e1 = -1; float v1 = -3.4e38f;
    #pragma unroll
    for (int e = 0; e < NE; ++e) if (e != e0 && gl[e] > v1) { v1 = gl[e]; e1 = e; }
    float ex = __expf(v1 - v0);
    float g0 = 1.f / (1.f + ex);
    float g1 = ex / (1.f + ex);

    atomicAdd(&impS[e0], g0);
    atomicAdd(&impS[e1], g1);

    float s = g0 * bpv[e0] + g1 * bpv[e1];
    for (int fb = 0; fb < 32; ++fb) {
        float4 xv = row4[fb];
        float x4[4] = {xv.x, xv.y, xv.z, xv.w};
        #pragma unroll
        for (int j = 0; j < 4; ++j) {
            int f = fb * 4 + j;
            s += x4[j] * (g0 * WeS[e0][f] + g1 * WeS[e1][f]);
        }
    }
    s = 10.f * tanhf(s) + ninf[t];

    red[n] = s;
    __syncthreads();
    for (int off = 64; off > 0; off >>= 1) {
        if (n < off) red[n] = fmaxf(red[n], red[n + off]);
        __syncthreads();
    }
    float mx = red[0];
    __syncthreads();
    float e = __expf(s - mx);
    red[n] = e;
    __syncthreads();
    for (int off = 64; off > 0; off >>= 1) {
        if (n < off) red[n] += red[n + off];
        __syncthreads();
    }
    float sum = red[0];

    out[t] = e / sum;

    if (n < NE) atomicAdd(&importance[n], impS[n]);
}

// ---------------------------------------------------------------------------
// K4: moe_loss from importance (f32 at out[T]).
// ---------------------------------------------------------------------------
__global__ void loss_kernel(const float* __restrict__ importance,
                            float* __restrict__ out) {
    if (threadIdx.x == 0) {
        float mean = 0.f;
        #pragma unroll
        for (int e = 0; e < NE; ++e) mean += importance[e];
        mean *= (1.f / NE);
        float var = 0.f;
        #pragma unroll
        for (int e = 0; e < NE; ++e) {
            float d = importance[e] - mean;
            var += d * d;
        }
        var *= (1.f / NE);
        out[T] = var / (mean * mean + 1e-10f);
    }
}

// ---------------------------------------------------------------------------
extern "C" void kernel_launch(void* const* d_in, const int* in_sizes, int n_in,
                              void* d_out, int out_size, void* d_ws, size_t ws_size,
                              hipStream_t stream) {
    const float* nodes  = (const float*)d_in[0];
    const float* routes = (const float*)d_in[1];
    const float* ninf   = (const float*)d_in[2];
    const float* rmask  = (const float*)d_in[3];
    const float* Wq     = (const float*)d_in[4];
    const float* Wk     = (const float*)d_in[5];
    const float* Wv     = (const float*)d_in[6];
    const float* Wg     = (const float*)d_in[7];
    const float* We     = (const float*)d_in[8];
    const float* be     = (const float*)d_in[9];
    const float* Wfin   = (const float*)d_in[10];

    // ws (f32 elems): [16..1040) We' | [1040..1048) b' | [1048..1056) importance
    // | [4096..) q | +T*HD k | +T*HD v | +T*HD xcat   (~105 MB)
    float* ws = (float*)d_ws;
    float* Wep        = ws + 16;
    float* bpv        = ws + 1040;
    float* importance = ws + 1048;
    float* qbuf       = ws + 4096;
    float* kbuf       = qbuf + (long)T * HD;
    float* vbuf       = kbuf + (long)T * HD;
    float* xcat       = vbuf + (long)T * HD;

    float* out = (float*)d_out;

    prep_kernel<<<NE, 128, 0, stream>>>(We, be, Wfin, Wep, bpv, importance);
    proj_kernel<<<dim3(800, 3), 128, 0, stream>>>(nodes, routes, Wq, Wk, Wv,
                                                  qbuf, kbuf, vbuf);
    attn_kernel<<<dim3(BP, H), 64, 0, stream>>>(qbuf, kbuf, vbuf,
                                                rmask, ninf, xcat);
    moe_final_kernel<<<BP, 128, 0, stream>>>(xcat, Wg, ninf, Wep, bpv,
                                             importance, out);
    loss_kernel<<<1, 64, 0, stream>>>(importance, out);
}